// Round 1
// baseline (73372.192 us; speedup 1.0000x reference)
//
#include <hip/hip_runtime.h>

// SNN: B=128, D0=512, T=512, layer dims 1024/1024/512, fp32, DECAY=0.5, THRESH=0.3
#define B_   128
#define D0_  512
#define T_   512
#define N1_  1024
#define N2_  1024
#define N3_  512

// Transpose inputs [B][D0][T] -> XT [T][B][D0] so per-step A-tiles are contiguous.
__global__ __launch_bounds__(256)
void transpose_bdt_to_tbd(const float* __restrict__ in, float* __restrict__ out)
{
    __shared__ float tile[32][33];   // +1 pad breaks bank conflicts on transpose read
    const int b  = blockIdx.z;
    const int d0 = blockIdx.x * 32;
    const int t0 = blockIdx.y * 32;
    const int tx = threadIdx.x & 31;
    const int ty = threadIdx.x >> 5;           // 0..7
#pragma unroll
    for (int r = 0; r < 4; ++r) {
        int d = ty + r * 8;
        tile[d][tx] = in[((long)b * D0_ + (d0 + d)) * T_ + (t0 + tx)]; // coalesced in t
    }
    __syncthreads();
#pragma unroll
    for (int r = 0; r < 4; ++r) {
        int t = ty + r * 8;
        out[((long)(t0 + t) * B_ + b) * D0_ + (d0 + tx)] = tile[tx][t]; // coalesced in d
    }
}

// One SNN layer stage: mem = mem*DECAY*(1-spk_prev) + A@W ; spk = (mem > THRESH)
// A: [128 x K] activations, element (b,k) at A[b*sb + k*sk]  (supports strided input slice)
// W: [K x N] row-major. mem/spk_in/spk_out: [128 x N] row-major.
// Block: 256 threads -> tile of 16 batches x 64 columns; each thread: 4 batches x 1 col.
__global__ __launch_bounds__(256)
void snn_layer(const float* __restrict__ A, long sb, long sk,
               const float* __restrict__ W,
               float* __restrict__ mem,
               const float* __restrict__ spk_in,
               float* __restrict__ spk_out,
               int K, int N)
{
    const int BK = 32;
    __shared__ float As[16][BK];               // 2 KB
    const int tid = threadIdx.x;
    const int j   = blockIdx.x * 64 + (tid & 63);
    const int bg  = tid >> 6;                  // 0..3 (wave-uniform)
    const int bt  = blockIdx.y * 16;
    const int bl  = bg * 4;                    // local batch base for this wave
    float acc[4] = {0.f, 0.f, 0.f, 0.f};

    for (int k0 = 0; k0 < K; k0 += BK) {
        __syncthreads();
        // stage 16x32 A-tile: 512 elems / 256 threads = 2 each
        for (int e = tid; e < 16 * BK; e += 256) {
            int bb = e >> 5;
            int kk = e & 31;
            As[bb][kk] = A[(long)(bt + bb) * sb + (long)(k0 + kk) * sk];
        }
        __syncthreads();
#pragma unroll
        for (int kk = 0; kk < BK; kk += 4) {
            const float* Wr = W + (long)(k0 + kk) * N + j;   // coalesced across lanes
            float w0 = Wr[0];
            float w1 = Wr[(long)N];
            float w2 = Wr[2L * N];
            float w3 = Wr[3L * N];
#pragma unroll
            for (int i = 0; i < 4; ++i) {
                float4 a = *(const float4*)&As[bl + i][kk];  // wave-broadcast ds_read_b128
                acc[i] += a.x * w0 + a.y * w1 + a.z * w2 + a.w * w3;
            }
        }
    }
#pragma unroll
    for (int i = 0; i < 4; ++i) {
        long idx = (long)(bt + bl + i) * N + j;
        float m  = mem[idx] * 0.5f * (1.0f - spk_in[idx]) + acc[i];
        mem[idx] = m;
        spk_out[idx] = (m > 0.3f) ? 1.0f : 0.0f;
    }
}

extern "C" void kernel_launch(void* const* d_in, const int* in_sizes, int n_in,
                              void* d_out, int out_size, void* d_ws, size_t ws_size,
                              hipStream_t stream)
{
    const float* inputs = (const float*)d_in[0];  // [128,512,512]
    const float* w0     = (const float*)d_in[1];  // [512,1024]
    const float* w1     = (const float*)d_in[2];  // [1024,1024]
    const float* w2     = (const float*)d_in[3];  // [1024,512]
    float* out = (float*)d_out;                   // [128,512]

    // workspace layout: states then optional transposed input
    float* mem0 = (float*)d_ws;
    float* spk0 = mem0 + (size_t)B_ * N1_;
    float* mem1 = spk0 + (size_t)B_ * N1_;
    float* spk1 = mem1 + (size_t)B_ * N2_;
    float* mem2 = spk1 + (size_t)B_ * N2_;
    float* spk2 = mem2 + (size_t)B_ * N3_;
    float* XT   = spk2 + (size_t)B_ * N3_;

    size_t stateBytes = (size_t)B_ * (2 * N1_ + 2 * N2_ + 2 * N3_) * sizeof(float); // 2.62 MB
    size_t xtBytes    = (size_t)T_ * B_ * D0_ * sizeof(float);                      // 134.2 MB
    bool useXT = (ws_size >= stateBytes + xtBytes);

    hipMemsetAsync(d_ws, 0, stateBytes, stream);  // zero mem/spk state every call

    if (useXT)
        transpose_bdt_to_tbd<<<dim3(16, 16, 128), 256, 0, stream>>>(inputs, XT);

    for (int t = 0; t < T_; ++t) {
        const float* A0; long sb, sk;
        if (useXT) { A0 = XT + (size_t)t * B_ * D0_; sb = D0_;            sk = 1;  }
        else       { A0 = inputs + t;                sb = (long)D0_ * T_; sk = T_; }

        // layer 0: x_t @ w0 -> mem0/spk0
        snn_layer<<<dim3(N1_ / 64, B_ / 16), 256, 0, stream>>>(
            A0, sb, sk, w0, mem0, spk0, spk0, D0_, N1_);
        // layer 1: spk0 @ w1 -> mem1/spk1
        snn_layer<<<dim3(N2_ / 64, B_ / 16), 256, 0, stream>>>(
            spk0, (long)N1_, 1L, w1, mem1, spk1, spk1, N1_, N2_);
        // layer 2: spk1 @ w2 -> mem2/spk2 (final step writes spikes straight to d_out)
        float* so = (t == T_ - 1) ? out : spk2;
        snn_layer<<<dim3(N3_ / 64, B_ / 16), 256, 0, stream>>>(
            spk1, (long)N2_, 1L, w2, mem2, spk2, so, N2_, N3_);
    }
}

// Round 2
// 9346.567 us; speedup vs baseline: 7.8502x; 7.8502x over previous
//
#include <hip/hip_runtime.h>

// SNN B=128, D0=512, T=512, dims 1024/1024/512, DECAY=0.5, THRESH=0.3
// Strategy: precompute I0 = X@w0 (parallel, MFMA 3-term split);
// per step: stage_mid (L1, split-bf16 MFMA, exact for binary spikes),
//           stage_last (L2 MFMA + fused L0 LIF update for t+1).

typedef __bf16 bf16;
typedef __attribute__((ext_vector_type(8))) __bf16 bf16x8;
typedef __attribute__((ext_vector_type(4))) float f32x4;

#define B_   128
#define D0_  512
#define T_   512
#define N1_  1024
#define N2_  1024
#define N3_  512
#define MFMA16(a,b,c) __builtin_amdgcn_mfma_f32_16x16x32_bf16((a),(b),(c),0,0,0)

// ---------- setup kernels (run once per call, fully parallel) ----------

// inputs [B][D0][T] fp32 -> Xh/Xl [T*B][D0] bf16 (hi/lo split, transposed)
__global__ __launch_bounds__(256)
void split_x(const float* __restrict__ in, bf16* __restrict__ Xh, bf16* __restrict__ Xl)
{
    __shared__ float tile[32][33];
    const int b = blockIdx.z, d0 = blockIdx.x * 32, t0 = blockIdx.y * 32;
    const int tx = threadIdx.x & 31, ty = threadIdx.x >> 5;
#pragma unroll
    for (int r = 0; r < 4; ++r) {
        int d = ty + r * 8;
        tile[d][tx] = in[((size_t)b * D0_ + d0 + d) * T_ + t0 + tx];
    }
    __syncthreads();
#pragma unroll
    for (int r = 0; r < 4; ++r) {
        int t = ty + r * 8;
        float v = tile[tx][t];
        bf16 h = (bf16)v;
        size_t o = ((size_t)(t0 + t) * B_ + b) * D0_ + d0 + tx;
        Xh[o] = h;
        Xl[o] = (bf16)(v - (float)h);
    }
}

// W [K][N] fp32 -> WTh/WTl [N][K] bf16 (transposed hi/lo split)
__global__ __launch_bounds__(256)
void split_w(const float* __restrict__ W, bf16* __restrict__ WTh, bf16* __restrict__ WTl,
             int K, int N)
{
    __shared__ float tile[32][33];
    const int k0 = blockIdx.x * 32, n0 = blockIdx.y * 32;
    const int tx = threadIdx.x & 31, ty = threadIdx.x >> 5;
#pragma unroll
    for (int r = 0; r < 4; ++r)
        tile[ty + r * 8][tx] = W[(size_t)(k0 + ty + r * 8) * N + n0 + tx];
    __syncthreads();
#pragma unroll
    for (int r = 0; r < 4; ++r) {
        int nl = ty + r * 8;
        float v = tile[tx][nl];
        bf16 h = (bf16)v;
        size_t o = (size_t)(n0 + nl) * K + k0 + tx;
        WTh[o] = h;
        WTl[o] = (bf16)(v - (float)h);
    }
}

// I0[(t*B+b)][n] = X[(t*B+b)][k] @ w0[k][n], 3-term split MFMA.
// grid (N1/64=16, 65536/64=1024), block 256 (4 waves, one 16-row m-frag each)
__global__ __launch_bounds__(256)
void gemm_I0(const bf16* __restrict__ Xh, const bf16* __restrict__ Xl,
             const bf16* __restrict__ WTh, const bf16* __restrict__ WTl,
             float* __restrict__ I0)
{
    const int tid = threadIdx.x, lane = tid & 63, w = tid >> 6;
    const int m0 = blockIdx.y * 64 + w * 16;
    const int nb = blockIdx.x * 64;
    const int q = lane >> 4, kq = q * 8;
    const int mr = m0 + (lane & 15);
    const int nl = nb + (lane & 15);
    const bf16* ahp = Xh + (size_t)mr * D0_ + kq;
    const bf16* alp = Xl + (size_t)mr * D0_ + kq;
    f32x4 acc[4] = {{0,0,0,0},{0,0,0,0},{0,0,0,0},{0,0,0,0}};
#pragma unroll 4
    for (int s = 0; s < 16; ++s) {            // K = 512 = 16 * 32
        bf16x8 xh = *(const bf16x8*)(ahp + s * 32);
        bf16x8 xl = *(const bf16x8*)(alp + s * 32);
#pragma unroll
        for (int f = 0; f < 4; ++f) {
            bf16x8 bh = *(const bf16x8*)(WTh + (size_t)(nl + f * 16) * D0_ + kq + s * 32);
            bf16x8 bl = *(const bf16x8*)(WTl + (size_t)(nl + f * 16) * D0_ + kq + s * 32);
            acc[f] = MFMA16(xh, bh, acc[f]);
            acc[f] = MFMA16(xl, bh, acc[f]);
            acc[f] = MFMA16(xh, bl, acc[f]);
        }
    }
#pragma unroll
    for (int f = 0; f < 4; ++f)
#pragma unroll
        for (int r = 0; r < 4; ++r)
            I0[(size_t)(m0 + q * 4 + r) * N1_ + nb + f * 16 + (lane & 15)] = acc[f][r];
}

// mem0(0) = I0(0) (initial mem/spk are zero), spk0 = H(mem0)
__global__ __launch_bounds__(256)
void init_l0(const float* __restrict__ I0, float* __restrict__ mem0, bf16* __restrict__ spk0b)
{
    int i = blockIdx.x * 256 + threadIdx.x;
    float m = I0[i];
    mem0[i] = m;
    spk0b[i] = (m > 0.3f) ? (bf16)1.0f : (bf16)0.0f;
}

// ---------- per-step stage kernels ----------

// L1: [128x1024] = spk0 @ w1, + LIF on mem1/spk1. grid (64,4), 4 waves: mh x kh
__global__ __launch_bounds__(256)
void stage_mid(const bf16* __restrict__ Ab,   // spk0b [128][1024]
               const bf16* __restrict__ WTh,  // [1024][1024]
               const bf16* __restrict__ WTl,
               float* __restrict__ mem, bf16* __restrict__ spkb)
{
    const int tid = threadIdx.x, lane = tid & 63, w = tid >> 6;
    const int mh = w & 1, kh = w >> 1;                 // K split 2-way (512 each)
    const int m0 = blockIdx.y * 32 + mh * 16;
    const int q = lane >> 4, kq = q * 8;
    const bf16* ap  = Ab  + (size_t)(m0 + (lane & 15)) * N1_ + kh * 512 + kq;
    const bf16* bhp = WTh + (size_t)(blockIdx.x * 16 + (lane & 15)) * N1_ + kh * 512 + kq;
    const bf16* blp = WTl + (size_t)(blockIdx.x * 16 + (lane & 15)) * N1_ + kh * 512 + kq;
    f32x4 acc = {0, 0, 0, 0};
#pragma unroll 8
    for (int s = 0; s < 16; ++s) {                     // 512 / 32
        bf16x8 a = *(const bf16x8*)(ap + s * 32);
        acc = MFMA16(a, *(const bf16x8*)(bhp + s * 32), acc);
        acc = MFMA16(a, *(const bf16x8*)(blp + s * 32), acc);
    }
    __shared__ f32x4 red[2][64];
    if (kh == 1) red[mh][lane] = acc;
    __syncthreads();
    if (kh == 0) {
        f32x4 o = red[mh][lane];
        acc.x += o.x; acc.y += o.y; acc.z += o.z; acc.w += o.w;
#pragma unroll
        for (int r = 0; r < 4; ++r) {
            size_t idx = (size_t)(m0 + q * 4 + r) * N2_ + blockIdx.x * 16 + (lane & 15);
            float m = mem[idx] * 0.5f * (1.0f - (float)spkb[idx]) + acc[r];
            mem[idx] = m;
            spkb[idx] = (m > 0.3f) ? (bf16)1.0f : (bf16)0.0f;
        }
    }
}

// L2: [128x512] = spk1 @ w2 + LIF on mem2/spk2; optional d_out store;
// fused L0 LIF update for step t+1 from precomputed I0. grid (32,8), 4-way K split
__global__ __launch_bounds__(256)
void stage_last(const bf16* __restrict__ Ab,   // spk1b [128][1024]
                const bf16* __restrict__ WTh,  // [512][1024]
                const bf16* __restrict__ WTl,
                float* __restrict__ mem, bf16* __restrict__ spkb,
                float* __restrict__ outp,          // d_out at t==T-1 else null
                const float* __restrict__ I0next,  // I0 + (t+1)*B*N1 or null
                float* __restrict__ mem0, bf16* __restrict__ spk0b)
{
    const int tid = threadIdx.x, lane = tid & 63, w = tid >> 6;   // w = K quarter
    const int m0 = blockIdx.y * 16;
    const int q = lane >> 4, kq = q * 8;
    const bf16* ap  = Ab  + (size_t)(m0 + (lane & 15)) * N2_ + w * 256 + kq;
    const bf16* bhp = WTh + (size_t)(blockIdx.x * 16 + (lane & 15)) * N2_ + w * 256 + kq;
    const bf16* blp = WTl + (size_t)(blockIdx.x * 16 + (lane & 15)) * N2_ + w * 256 + kq;
    f32x4 acc = {0, 0, 0, 0};
#pragma unroll 4
    for (int s = 0; s < 8; ++s) {                      // 256 / 32
        bf16x8 a = *(const bf16x8*)(ap + s * 32);
        acc = MFMA16(a, *(const bf16x8*)(bhp + s * 32), acc);
        acc = MFMA16(a, *(const bf16x8*)(blp + s * 32), acc);
    }
    __shared__ f32x4 red[3][64];
    if (w) red[w - 1][lane] = acc;
    __syncthreads();
    if (w == 0) {
#pragma unroll
        for (int j = 0; j < 3; ++j) {
            f32x4 o = red[j][lane];
            acc.x += o.x; acc.y += o.y; acc.z += o.z; acc.w += o.w;
        }
#pragma unroll
        for (int r = 0; r < 4; ++r) {
            size_t idx = (size_t)(m0 + q * 4 + r) * N3_ + blockIdx.x * 16 + (lane & 15);
            float m = mem[idx] * 0.5f * (1.0f - (float)spkb[idx]) + acc[r];
            mem[idx] = m;
            spkb[idx] = (m > 0.3f) ? (bf16)1.0f : (bf16)0.0f;
            if (outp) outp[idx] = (m > 0.3f) ? 1.0f : 0.0f;
        }
    }
    if (I0next) {  // L0 LIF for t+1: 131072 elems over 256 blocks x 256 thr
        int base = (blockIdx.y * gridDim.x + blockIdx.x) * 512 + tid;
#pragma unroll
        for (int e = 0; e < 2; ++e) {
            int i = base + e * 256;
            float m = mem0[i] * 0.5f * (1.0f - (float)spk0b[i]) + I0next[i];
            mem0[i] = m;
            spk0b[i] = (m > 0.3f) ? (bf16)1.0f : (bf16)0.0f;
        }
    }
}

// Tier-3 fallback: L0 stage computed per step from raw x (strided), on-the-fly split
__global__ __launch_bounds__(256)
void stage_l0_raw(const float* __restrict__ x, int t,
                  const bf16* __restrict__ WTh, const bf16* __restrict__ WTl, // [1024][512]
                  float* __restrict__ mem0, bf16* __restrict__ spk0b)
{
    const int tid = threadIdx.x, lane = tid & 63, w = tid >> 6;
    const int mh = w & 1, kh = w >> 1;                 // K=512 split 2-way
    const int m0 = blockIdx.y * 32 + mh * 16;
    const int q = lane >> 4, kq = q * 8;
    const int row = m0 + (lane & 15);
    const bf16* bhp = WTh + (size_t)(blockIdx.x * 16 + (lane & 15)) * D0_ + kh * 256 + kq;
    const bf16* blp = WTl + (size_t)(blockIdx.x * 16 + (lane & 15)) * D0_ + kh * 256 + kq;
    const float* xp = x + ((size_t)row * D0_ + kh * 256 + kq) * T_ + t;
    f32x4 acc = {0, 0, 0, 0};
#pragma unroll 2
    for (int s = 0; s < 8; ++s) {
        bf16x8 ah, al;
#pragma unroll
        for (int j = 0; j < 8; ++j) {
            float v = xp[(size_t)(s * 32 + j) * T_];
            bf16 h = (bf16)v;
            ah[j] = h;
            al[j] = (bf16)(v - (float)h);
        }
        bf16x8 bh = *(const bf16x8*)(bhp + s * 32);
        bf16x8 bl = *(const bf16x8*)(blp + s * 32);
        acc = MFMA16(ah, bh, acc);
        acc = MFMA16(al, bh, acc);
        acc = MFMA16(ah, bl, acc);
    }
    __shared__ f32x4 red[2][64];
    if (kh == 1) red[mh][lane] = acc;
    __syncthreads();
    if (kh == 0) {
        f32x4 o = red[mh][lane];
        acc.x += o.x; acc.y += o.y; acc.z += o.z; acc.w += o.w;
#pragma unroll
        for (int r = 0; r < 4; ++r) {
            size_t idx = (size_t)(m0 + q * 4 + r) * N1_ + blockIdx.x * 16 + (lane & 15);
            float m = mem0[idx] * 0.5f * (1.0f - (float)spk0b[idx]) + acc[r];
            mem0[idx] = m;
            spk0b[idx] = (m > 0.3f) ? (bf16)1.0f : (bf16)0.0f;
        }
    }
}

extern "C" void kernel_launch(void* const* d_in, const int* in_sizes, int n_in,
                              void* d_out, int out_size, void* d_ws, size_t ws_size,
                              hipStream_t stream)
{
    const float* x  = (const float*)d_in[0];
    const float* w0 = (const float*)d_in[1];
    const float* w1 = (const float*)d_in[2];
    const float* w2 = (const float*)d_in[3];
    float* out = (float*)d_out;

    char* p = (char*)d_ws;
    // states (contiguous, memset to 0)
    float* mem0 = (float*)p;            p += (size_t)B_ * N1_ * 4;
    bf16*  spk0b = (bf16*)p;            p += (size_t)B_ * N1_ * 2;
    float* mem1 = (float*)p;            p += (size_t)B_ * N2_ * 4;
    bf16*  spk1b = (bf16*)p;            p += (size_t)B_ * N2_ * 2;
    float* mem2 = (float*)p;            p += (size_t)B_ * N3_ * 4;
    bf16*  spk2b = (bf16*)p;            p += (size_t)B_ * N3_ * 2;
    size_t stateBytes = (size_t)(p - (char*)d_ws);
    // weight splits
    bf16* w0h = (bf16*)p;  p += (size_t)N1_ * D0_ * 2;
    bf16* w0l = (bf16*)p;  p += (size_t)N1_ * D0_ * 2;
    bf16* w1h = (bf16*)p;  p += (size_t)N2_ * N1_ * 2;
    bf16* w1l = (bf16*)p;  p += (size_t)N2_ * N1_ * 2;
    bf16* w2h = (bf16*)p;  p += (size_t)N3_ * N2_ * 2;
    bf16* w2l = (bf16*)p;  p += (size_t)N3_ * N2_ * 2;
    size_t baseBytes = (size_t)(p - (char*)d_ws);
    // big buffers (tier 1 only)
    bf16* Xh = (bf16*)p;   p += (size_t)T_ * B_ * D0_ * 2;
    bf16* Xl = (bf16*)p;   p += (size_t)T_ * B_ * D0_ * 2;
    float* I0 = (float*)p; p += (size_t)T_ * B_ * N1_ * 4;
    size_t fullBytes = (size_t)(p - (char*)d_ws);

    bool tier1 = (ws_size >= fullBytes);

    hipMemsetAsync(d_ws, 0, stateBytes, stream);
    split_w<<<dim3(D0_/32, N1_/32), 256, 0, stream>>>(w0, w0h, w0l, D0_, N1_);
    split_w<<<dim3(N1_/32, N2_/32), 256, 0, stream>>>(w1, w1h, w1l, N1_, N2_);
    split_w<<<dim3(N2_/32, N3_/32), 256, 0, stream>>>(w2, w2h, w2l, N2_, N3_);

    if (tier1) {
        split_x<<<dim3(D0_/32, T_/32, B_), 256, 0, stream>>>(x, Xh, Xl);
        gemm_I0<<<dim3(N1_/64, (T_*B_)/64), 256, 0, stream>>>(Xh, Xl, w0h, w0l, I0);
        init_l0<<<(B_*N1_)/256, 256, 0, stream>>>(I0, mem0, spk0b);
        for (int t = 0; t < T_; ++t) {
            stage_mid<<<dim3(N2_/16, B_/32), 256, 0, stream>>>(spk0b, w1h, w1l, mem1, spk1b);
            stage_last<<<dim3(N3_/16, B_/16), 256, 0, stream>>>(
                spk1b, w2h, w2l, mem2, spk2b,
                (t == T_-1) ? out : nullptr,
                (t < T_-1) ? (I0 + (size_t)(t+1) * B_ * N1_) : nullptr,
                mem0, spk0b);
        }
    } else {
        (void)baseBytes;
        for (int t = 0; t < T_; ++t) {
            stage_l0_raw<<<dim3(N1_/16, B_/32), 256, 0, stream>>>(x, t, w0h, w0l, mem0, spk0b);
            stage_mid<<<dim3(N2_/16, B_/32), 256, 0, stream>>>(spk0b, w1h, w1l, mem1, spk1b);
            stage_last<<<dim3(N3_/16, B_/16), 256, 0, stream>>>(
                spk1b, w2h, w2l, mem2, spk2b,
                (t == T_-1) ? out : nullptr,
                nullptr, mem0, spk0b);
        }
    }
}